// Round 16
// baseline (215.854 us; speedup 1.0000x reference)
//
#include <hip/hip_runtime.h>

typedef __attribute__((ext_vector_type(8))) short short8;
typedef __attribute__((ext_vector_type(4))) float f32x4;
typedef __attribute__((ext_vector_type(16))) float f32x16;
typedef __attribute__((ext_vector_type(4))) unsigned short us4;
typedef __attribute__((ext_vector_type(4))) unsigned int u32x4;

#define GLOAD16(gsrc, ldst)                                             \
  __builtin_amdgcn_global_load_lds(                                     \
      (const __attribute__((address_space(1))) unsigned int*)(gsrc),    \
      (__attribute__((address_space(3))) unsigned int*)(ldst), 16, 0, 0)

#define SB() __builtin_amdgcn_sched_barrier(0)
#define BAR() __builtin_amdgcn_s_barrier()
#define WAITV(N) asm volatile("s_waitcnt vmcnt(" #N ")" ::: "memory")
#define WAITL0() asm volatile("s_waitcnt lgkmcnt(0)" ::: "memory")

// Explicit VMEM drain + scheduler pin before a barrier that publishes
// global_load_lds data (r7-proven race fix).
#define VMEM_DRAIN_BARRIER()                              \
  do {                                                    \
    asm volatile("s_waitcnt vmcnt(0)" ::: "memory");      \
    __builtin_amdgcn_sched_barrier(0);                    \
    __syncthreads();                                      \
  } while (0)

#if __has_builtin(__builtin_amdgcn_exp2f)
#define EXP2F(x) __builtin_amdgcn_exp2f(x)
#else
#define EXP2F(x) exp2f(x)
#endif

static __device__ __forceinline__ unsigned short f2bf(float f) {
  unsigned int u = __float_as_uint(f);
  u += 0x7fffu + ((u >> 16) & 1u);          // RNE
  return (unsigned short)(u >> 16);
}

static __device__ __forceinline__ unsigned cvtpk(float lo, float hi) {
  unsigned r;
  asm("v_cvt_pk_bf16_f32 %0, %1, %2" : "=v"(r) : "v"(lo), "v"(hi));
  return r;
}

// ---------------------------------------------------------------------------
// 1) prep (fused): blocks [0,2048): x,y -> XY bf16, z -> Z bf16;
//    blocks [2048,3072): 4x weight f32 -> bf16 transpose (256 blocks each).
// ---------------------------------------------------------------------------
__global__ __launch_bounds__(256) void prep(const float* __restrict__ x,
                                            const float* __restrict__ y,
                                            const float* __restrict__ z,
                                            const float* __restrict__ Wq,
                                            const float* __restrict__ Wk,
                                            const float* __restrict__ Wv,
                                            const float* __restrict__ Wo,
                                            unsigned short* __restrict__ XY,
                                            unsigned short* __restrict__ Z,
                                            unsigned short* __restrict__ WqT,
                                            unsigned short* __restrict__ WkT,
                                            unsigned short* __restrict__ WvT,
                                            unsigned short* __restrict__ WoT) {
  __shared__ __align__(16) unsigned short LT[64 * 72];
  const int bid = blockIdx.x, t = threadIdx.x;

  if (bid < 2048) {
    const int NX = (8192 * 512) / 4;
    const int NZ = (8192 * 1024) / 4;
    const int total = 2 * NX + NZ;
    for (int idx = bid * 256 + t; idx < total; idx += 2048 * 256) {
      const float* src;
      unsigned short* dst;
      if (idx < NX) {
        int p = idx * 4; int row = p >> 9, c = p & 511;
        src = x + p; dst = XY + (size_t)row * 1024 + c;
      } else if (idx < 2 * NX) {
        int p = (idx - NX) * 4; int row = p >> 9, c = p & 511;
        src = y + p; dst = XY + (size_t)row * 1024 + 512 + c;
      } else {
        int p = (idx - 2 * NX) * 4;
        src = z + p; dst = Z + p;
      }
      float4 v = *(const float4*)src;
      us4 o; o[0] = f2bf(v.x); o[1] = f2bf(v.y); o[2] = f2bf(v.z); o[3] = f2bf(v.w);
      *(us4*)dst = o;
    }
    return;
  }

  const int seg = (bid - 2048) >> 8;          // 0..3
  const int local = (bid - 2048) & 255;
  const float* W = (seg == 0) ? Wq : (seg == 1) ? Wk : (seg == 2) ? Wv : Wo;
  unsigned short* WT = (seg == 0) ? WqT : (seg == 1) ? WkT : (seg == 2) ? WvT : WoT;
  const int k0 = (local >> 4) * 64, n0 = (local & 15) * 64;
#pragma unroll
  for (int j = 0; j < 4; ++j) {
    int r = j * 16 + (t >> 4);
    int c = (t & 15) * 4;
    float4 w = *(const float4*)(W + (size_t)(k0 + r) * 1024 + n0 + c);
    LT[(c + 0) * 72 + r] = f2bf(w.x);
    LT[(c + 1) * 72 + r] = f2bf(w.y);
    LT[(c + 2) * 72 + r] = f2bf(w.z);
    LT[(c + 3) * 72 + r] = f2bf(w.w);
  }
  __syncthreads();
#pragma unroll
  for (int j = 0; j < 2; ++j) {
    int n = j * 32 + (t >> 3), ch = t & 7;
    *(short8*)(WT + (size_t)(n0 + n) * 1024 + k0 + ch * 8) =
        *(const short8*)(LT + n * 72 + ch * 8);
  }
}

// ---------------------------------------------------------------------------
// 2a) fused QKV projection — 256x256 tile, 8-wave, 4-phase/K-tile schedule
//     (T3+T4 port): per phase {ds_read frags; stage 1 half-tile; s_barrier;
//     lgkmcnt(0); 16 MFMA (setprio); s_barrier}; counted vmcnt(4) once per
//     K-tile. LDS 128KB = A,B x dbuf x 2 halves. B-frags (both K-slices)
//     loaded once per K-tile at p0 and held in registers.
//     Stage order p0:A0(kt+1) p1:A1(kt+1) p2:B0(kt+2) p3:B1(kt+2) — each
//     dest region is barrier-separated from its last reader before issue.
// ---------------------------------------------------------------------------
__global__ __launch_bounds__(512, 1) void qkv_gemm8(
    const unsigned short* __restrict__ XY, const unsigned short* __restrict__ Zb,
    const unsigned short* __restrict__ WqT, const unsigned short* __restrict__ WkT,
    const unsigned short* __restrict__ WvT, unsigned short* __restrict__ Qb,
    unsigned short* __restrict__ Kb, unsigned short* __restrict__ Vtg) {
  __shared__ __align__(16) unsigned short As_[2][2][128 * 64];  // [buf][half]
  __shared__ __align__(16) unsigned short Bs_[2][2][128 * 64];

  const int tid = threadIdx.x;
  const int lane = tid & 63, w = tid >> 6;      // 8 waves
  const int lq = lane & 15, lg = lane >> 4;
  const int wr = w >> 2, wc = w & 3;            // 2 x 4 wave grid
  const int seg = blockIdx.x >> 2;
  const int n0 = (blockIdx.x & 3) * 256, m0 = blockIdx.y * 256;

  const unsigned short* A;
  const unsigned short* Bt;
  float scale;
  if (seg == 0)      { A = XY; Bt = WqT; scale = 0.18033688011112042f; }
  else if (seg == 1) { A = Zb; Bt = WkT; scale = 1.0f; }
  else               { A = Zb; Bt = WvT; scale = 1.0f; }

  // staging geometry: 2 rounds x 512 thr x 16B = one 128x64 half (16KB)
  const int sr_ = tid >> 3;                    // 0..63 (row within round)
  const int gg_ = (tid & 7) ^ (sr_ & 7);       // pre-swizzled source chunk

#define STAGE_A(kt1, h)                                                       \
  do { int b_ = (kt1) & 1, kk_ = ((kt1) & 15) * 64;                           \
    _Pragma("unroll")                                                         \
    for (int i = 0; i < 2; ++i) {                                             \
      int r_ = i * 64 + sr_;                                                  \
      GLOAD16(A + (size_t)(m0 + (h) * 128 + r_) * 1024 + kk_ + gg_ * 8,       \
              (char*)As_[b_][h] + i * 8192 + w * 1024);                       \
    } } while (0)

#define STAGE_B(kt1, h)                                                       \
  do { int b_ = (kt1) & 1, kk_ = ((kt1) & 15) * 64;                           \
    _Pragma("unroll")                                                         \
    for (int i = 0; i < 2; ++i) {                                             \
      int r_ = i * 64 + sr_;                                                  \
      GLOAD16(Bt + (size_t)(n0 + (h) * 128 + r_) * 1024 + kk_ + gg_ * 8,      \
              (char*)Bs_[b_][h] + i * 8192 + w * 1024);                       \
    } } while (0)

  f32x4 acc[8][4] = {};

  // prologue: kt0 complete + B halves of kt1; then vmcnt(4) -> kt0 landed
  STAGE_A(0, 0); STAGE_A(0, 1); STAGE_B(0, 0); STAGE_B(0, 1);
  STAGE_B(1, 0); STAGE_B(1, 1);
  WAITV(4); SB();
  __syncthreads();

#pragma unroll 2
  for (int kt = 0; kt < 16; ++kt) {
    const int cb = kt & 1;
    const unsigned short* Ac = As_[cb][wr];        // wave's own A half
    const unsigned short* Bc = Bs_[cb][wc >> 1];   // wave's B half
    const int brow = (wc & 1) * 64;

    short8 bfr0[4], bfr1[4], af[4];

    // ---- phase 0: B both K-slices + A mf0..3 ks0; stage A0(kt+1)
#pragma unroll
    for (int nf = 0; nf < 4; ++nf) {
      int r = brow + nf * 16 + lq;
      bfr0[nf] = *(const short8*)(Bc + r * 64 + ((lg ^ (r & 7)) * 8));
      bfr1[nf] = *(const short8*)(Bc + r * 64 + (((4 + lg) ^ (r & 7)) * 8));
    }
#pragma unroll
    for (int mf = 0; mf < 4; ++mf) {
      int r = mf * 16 + lq;
      af[mf] = *(const short8*)(Ac + r * 64 + ((lg ^ (r & 7)) * 8));
    }
    STAGE_A(kt + 1, 0);
    SB(); BAR(); WAITL0(); SB();
    __builtin_amdgcn_s_setprio(1);
#pragma unroll
    for (int mf = 0; mf < 4; ++mf)
#pragma unroll
      for (int nf = 0; nf < 4; ++nf)
        acc[mf][nf] = __builtin_amdgcn_mfma_f32_16x16x32_bf16(af[mf], bfr0[nf],
                                                              acc[mf][nf], 0, 0, 0);
    __builtin_amdgcn_s_setprio(0);
    SB(); BAR(); SB();

    // ---- phase 1: A mf4..7 ks0; stage A1(kt+1)
#pragma unroll
    for (int mf = 0; mf < 4; ++mf) {
      int r = 64 + mf * 16 + lq;
      af[mf] = *(const short8*)(Ac + r * 64 + ((lg ^ (r & 7)) * 8));
    }
    STAGE_A(kt + 1, 1);
    SB(); BAR(); WAITL0(); SB();
    __builtin_amdgcn_s_setprio(1);
#pragma unroll
    for (int mf = 0; mf < 4; ++mf)
#pragma unroll
      for (int nf = 0; nf < 4; ++nf)
        acc[4 + mf][nf] = __builtin_amdgcn_mfma_f32_16x16x32_bf16(af[mf], bfr0[nf],
                                                                  acc[4 + mf][nf], 0, 0, 0);
    __builtin_amdgcn_s_setprio(0);
    SB(); BAR(); SB();

    // ---- phase 2: A mf0..3 ks1; stage B0(kt+2)
#pragma unroll
    for (int mf = 0; mf < 4; ++mf) {
      int r = mf * 16 + lq;
      af[mf] = *(const short8*)(Ac + r * 64 + (((4 + lg) ^ (r & 7)) * 8));
    }
    STAGE_B(kt + 2, 0);
    SB(); BAR(); WAITL0(); SB();
    __builtin_amdgcn_s_setprio(1);
#pragma unroll
    for (int mf = 0; mf < 4; ++mf)
#pragma unroll
      for (int nf = 0; nf < 4; ++nf)
        acc[mf][nf] = __builtin_amdgcn_mfma_f32_16x16x32_bf16(af[mf], bfr1[nf],
                                                              acc[mf][nf], 0, 0, 0);
    __builtin_amdgcn_s_setprio(0);
    SB(); BAR(); SB();

    // ---- phase 3: A mf4..7 ks1; stage B1(kt+2); vmcnt(4) for next kt
#pragma unroll
    for (int mf = 0; mf < 4; ++mf) {
      int r = 64 + mf * 16 + lq;
      af[mf] = *(const short8*)(Ac + r * 64 + (((4 + lg) ^ (r & 7)) * 8));
    }
    STAGE_B(kt + 2, 1);
    SB(); BAR(); WAITL0(); SB();
    __builtin_amdgcn_s_setprio(1);
#pragma unroll
    for (int mf = 0; mf < 4; ++mf)
#pragma unroll
      for (int nf = 0; nf < 4; ++nf)
        acc[4 + mf][nf] = __builtin_amdgcn_mfma_f32_16x16x32_bf16(af[mf], bfr1[nf],
                                                                  acc[4 + mf][nf], 0, 0, 0);
    __builtin_amdgcn_s_setprio(0);
    WAITV(4); SB(); BAR(); SB();
  }
#undef STAGE_A
#undef STAGE_B

  // ---- epilogue
  if (seg == 2) {
    const int bq = m0 >> 11;
#pragma unroll
    for (int mf = 0; mf < 8; ++mf)
#pragma unroll
      for (int nf = 0; nf < 4; ++nf) {
        int col = n0 + wc * 64 + nf * 16 + lq;
        int hh = col >> 6, dd = col & 63;
        int row = m0 + wr * 128 + mf * 16 + lg * 4;
        int s = row & 2047;
        us4 o4;
#pragma unroll
        for (int j = 0; j < 4; ++j) o4[j] = f2bf(acc[mf][nf][j]);
        *(us4*)(Vtg + ((size_t)(bq * 16 + hh) * 64 + dd) * 2048 + s) = o4;
      }
  } else {
    unsigned short* C = (seg == 0) ? Qb : Kb;
#pragma unroll
    for (int mf = 0; mf < 8; ++mf)
#pragma unroll
      for (int nf = 0; nf < 4; ++nf)
#pragma unroll
        for (int j = 0; j < 4; ++j) {
          int row = m0 + wr * 128 + mf * 16 + lg * 4 + j;
          int col = n0 + wc * 64 + nf * 16 + lq;
          C[(size_t)row * 1024 + col] = f2bf(acc[mf][nf][j] * scale);
        }
  }
}

// ---------------------------------------------------------------------------
// 2b) NT GEMM (Wo): C[8192][1024] = A @ Bt^T, f32 out; BK=64 (r13-proven)
// ---------------------------------------------------------------------------
__global__ __launch_bounds__(256) void gemm_nt(const unsigned short* __restrict__ A,
                                               const unsigned short* __restrict__ Bt,
                                               float* __restrict__ Cout) {
  __shared__ __align__(16) unsigned short As[128 * 64];
  __shared__ __align__(16) unsigned short Bs[128 * 64];
  const int tid = threadIdx.x;
  const int lane = tid & 63, wid = tid >> 6;
  const int lq = lane & 15, lg = lane >> 4;
  const int wr = wid >> 1, wc = wid & 1;
  const int m0 = blockIdx.y * 128, n0 = blockIdx.x * 128;

  const int srr = tid >> 3;
  const int gg = (tid & 7) ^ (srr & 7);

  f32x4 acc[4][4] = {};

  for (int k0 = 0; k0 < 1024; k0 += 64) {
    __syncthreads();
#pragma unroll
    for (int i = 0; i < 4; ++i) {
      int r = i * 32 + srr;
      GLOAD16(A + (size_t)(m0 + r) * 1024 + k0 + gg * 8,
              (char*)As + i * 4096 + wid * 1024);
      GLOAD16(Bt + (size_t)(n0 + r) * 1024 + k0 + gg * 8,
              (char*)Bs + i * 4096 + wid * 1024);
    }
    VMEM_DRAIN_BARRIER();
#pragma unroll
    for (int kk = 0; kk < 2; ++kk) {
      short8 af[4], bfr[4];
#pragma unroll
      for (int mf = 0; mf < 4; ++mf) {
        int r = wr * 64 + mf * 16 + lq;
        int c = (kk * 4 + lg) ^ (r & 7);
        af[mf] = *(const short8*)(As + r * 64 + c * 8);
      }
#pragma unroll
      for (int nf = 0; nf < 4; ++nf) {
        int r = wc * 64 + nf * 16 + lq;
        int c = (kk * 4 + lg) ^ (r & 7);
        bfr[nf] = *(const short8*)(Bs + r * 64 + c * 8);
      }
#pragma unroll
      for (int mf = 0; mf < 4; ++mf)
#pragma unroll
        for (int nf = 0; nf < 4; ++nf)
          acc[mf][nf] = __builtin_amdgcn_mfma_f32_16x16x32_bf16(af[mf], bfr[nf],
                                                                acc[mf][nf], 0, 0, 0);
    }
  }

#pragma unroll
  for (int mf = 0; mf < 4; ++mf)
#pragma unroll
    for (int nf = 0; nf < 4; ++nf)
#pragma unroll
      for (int j = 0; j < 4; ++j) {
        int row = m0 + wr * 64 + mf * 16 + lg * 4 + j;
        int col = n0 + wc * 64 + nf * 16 + lq;
        Cout[(size_t)row * 1024 + col] = acc[mf][nf][j];
      }
}

// ---------------------------------------------------------------------------
// 3) flash attention v8 (r10-proven): 8 waves x 32 q = 256 q/block;
//    KVBLK=64 double-buffered; XCD remap; ones-MFMA row-sum; permlane pack.
// ---------------------------------------------------------------------------
__global__ __launch_bounds__(512, 4) void attn8(const unsigned short* __restrict__ Q,
                                                const unsigned short* __restrict__ K,
                                                const unsigned short* __restrict__ Vt,
                                                unsigned short* __restrict__ AO) {
  __shared__ __align__(16) unsigned short Ks[2][64 * 64];  // [kv][d]
  __shared__ __align__(16) unsigned short Vs[2][64 * 64];  // [d][kv]

  const int lin = blockIdx.x + (blockIdx.y << 3);  // 0..511
  const int xcd = lin & 7, rest = lin >> 3;
  const int bh = xcd * 8 + (rest >> 3);
  const int q0 = (rest & 7) * 256;
  const int b = bh >> 4, h = bh & 15;

  const int tid = threadIdx.x, lane = tid & 63, w = tid >> 6;
  const int l31 = lane & 31, hi = lane >> 5;
  const int swz = l31 & 7;

  short8 qf[4];
#pragma unroll
  for (int dblk = 0; dblk < 4; ++dblk)
    qf[dblk] = *(const short8*)(Q + (size_t)(b * 2048 + q0 + w * 32 + l31) * 1024 +
                                h * 64 + dblk * 16 + hi * 8);

  short8 ones;
#pragma unroll
  for (int e = 0; e < 8; ++e) ones[e] = (short)0x3F80;

#define STAGE(bf, t)                                                               \
  do {                                                                             \
    {                                                                              \
      int r = tid >> 3, c = tid & 7, g = c ^ (r & 7);                              \
      GLOAD16(K + (size_t)(b * 2048 + (t) * 64 + r) * 1024 + h * 64 + g * 8,       \
              (char*)Ks[bf] + w * 1024);                                           \
      GLOAD16(Vt + ((size_t)bh * 64 + r) * 2048 + (t) * 64 + g * 8,                \
              (char*)Vs[bf] + w * 1024);                                           \
    }                                                                              \
  } while (0)

  STAGE(0, 0);
  VMEM_DRAIN_BARRIER();

  f32x16 od[2] = {};
  f32x16 sums = {};
  int buf = 0;

  for (int t = 0; t < 32; ++t) {
    if (t < 31) STAGE(buf ^ 1, t + 1);

    f32x16 st[2];
    __builtin_amdgcn_s_setprio(1);
#pragma unroll
    for (int kh = 0; kh < 2; ++kh) {
      f32x16 a = {};
#pragma unroll
      for (int dblk = 0; dblk < 4; ++dblk) {
        short8 kf = *(const short8*)(Ks[buf] + (kh * 32 + l31) * 64 +
                                     (((dblk * 2 + hi) ^ swz) * 8));
        a = __builtin_amdgcn_mfma_f32_32x32x16_bf16(kf, qf[dblk], a, 0, 0, 0);
      }
      st[kh] = a;
    }
    __builtin_amdgcn_s_setprio(0);

#pragma unroll
    for (int kh = 0; kh < 2; ++kh)
#pragma unroll
      for (int r = 0; r < 16; ++r) st[kh][r] = EXP2F(st[kh][r]);

    __builtin_amdgcn_s_setprio(1);
#pragma unroll
    for (int ks = 0; ks < 4; ++ks) {
      const int tt = ks >> 1, cm = (ks & 1) * 2;
      unsigned a_lo = cvtpk(st[tt][cm * 4 + 0], st[tt][cm * 4 + 1]);
      unsigned a_hi = cvtpk(st[tt][cm * 4 + 2], st[tt][cm * 4 + 3]);
      unsigned b_lo = cvtpk(st[tt][cm * 4 + 4], st[tt][cm * 4 + 5]);
      unsigned b_hi = cvtpk(st[tt][cm * 4 + 6], st[tt][cm * 4 + 7]);
      auto Xlo = __builtin_amdgcn_permlane32_swap(a_lo, b_lo, false, false);
      auto Xhi = __builtin_amdgcn_permlane32_swap(a_hi, b_hi, false, false);
      u32x4 up;
      up[0] = Xlo[0];
      up[1] = Xhi[0];
      up[2] = Xlo[1];
      up[3] = Xhi[1];
      short8 pa = __builtin_bit_cast(short8, up);
      sums = __builtin_amdgcn_mfma_f32_32x32x16_bf16(ones, pa, sums, 0, 0, 0);
#pragma unroll
      for (int td = 0; td < 2; ++td) {
        short8 vf = *(const short8*)(Vs[buf] + (td * 32 + l31) * 64 +
                                     (((ks * 2 + hi) ^ swz) * 8));
        od[td] = __builtin_amdgcn_mfma_f32_32x32x16_bf16(vf, pa, od[td], 0, 0, 0);
      }
    }
    __builtin_amdgcn_s_setprio(0);

    VMEM_DRAIN_BARRIER();
    buf ^= 1;
  }

  float inv = 1.0f / sums[0];
  const size_t orow = (size_t)(b * 2048 + q0 + w * 32 + l31);
#pragma unroll
  for (int td = 0; td < 2; ++td)
#pragma unroll
    for (int rh = 0; rh < 4; ++rh) {
      us4 o4;
#pragma unroll
      for (int rl = 0; rl < 4; ++rl) o4[rl] = f2bf(od[td][rh * 4 + rl] * inv);
      *(us4*)(AO + orow * 1024 + h * 64 + td * 32 + rh * 8 + hi * 4) = o4;
    }
#undef STAGE
}

// ---------------------------------------------------------------------------
extern "C" void kernel_launch(void* const* d_in, const int* in_sizes, int n_in,
                              void* d_out, int out_size, void* d_ws, size_t ws_size,
                              hipStream_t stream) {
  const float* x = (const float*)d_in[0];
  const float* y = (const float*)d_in[1];
  const float* z = (const float*)d_in[2];
  const float* Wq = (const float*)d_in[3];
  const float* Wk = (const float*)d_in[4];
  const float* Wv = (const float*)d_in[5];
  const float* Wo = (const float*)d_in[6];

  char* ws = (char*)d_ws;
  unsigned short* XY  = (unsigned short*)(ws + 0);
  unsigned short* Zb  = (unsigned short*)(ws + 16777216);
  unsigned short* WqT = (unsigned short*)(ws + 33554432);
  unsigned short* WkT = (unsigned short*)(ws + 35651584);
  unsigned short* WvT = (unsigned short*)(ws + 37748736);
  unsigned short* WoT = (unsigned short*)(ws + 39845888);
  unsigned short* Qb  = (unsigned short*)(ws + 41943040);
  unsigned short* Kb  = (unsigned short*)(ws + 58720256);
  unsigned short* Vtg = (unsigned short*)(ws + 92274688);
  unsigned short* AO  = (unsigned short*)(ws + 109051904);

  prep<<<3072, 256, 0, stream>>>(x, y, z, Wq, Wk, Wv, Wo,
                                 XY, Zb, WqT, WkT, WvT, WoT);

  // fused QKV projection, 8-phase 256^2; V direct to Vt[bh][d][s]
  qkv_gemm8<<<dim3(12, 32), 512, 0, stream>>>(XY, Zb, WqT, WkT, WvT, Qb, Kb, Vtg);

  attn8<<<dim3(8, 64), 512, 0, stream>>>(Qb, Kb, Vtg, AO);

  gemm_nt<<<dim3(8, 64), 256, 0, stream>>>(AO, WoT, (float*)d_out);
}

// Round 17
// 195.909 us; speedup vs baseline: 1.1018x; 1.1018x over previous
//
#include <hip/hip_runtime.h>

typedef __attribute__((ext_vector_type(8))) short short8;
typedef __attribute__((ext_vector_type(4))) float f32x4;
typedef __attribute__((ext_vector_type(16))) float f32x16;
typedef __attribute__((ext_vector_type(4))) unsigned short us4;
typedef __attribute__((ext_vector_type(4))) unsigned int u32x4;

#define GLOAD16(gsrc, ldst)                                             \
  __builtin_amdgcn_global_load_lds(                                     \
      (const __attribute__((address_space(1))) unsigned int*)(gsrc),    \
      (__attribute__((address_space(3))) unsigned int*)(ldst), 16, 0, 0)

// Explicit VMEM drain + scheduler pin before a barrier that publishes
// global_load_lds data (r7-proven race fix).
#define VMEM_DRAIN_BARRIER()                              \
  do {                                                    \
    asm volatile("s_waitcnt vmcnt(0)" ::: "memory");      \
    __builtin_amdgcn_sched_barrier(0);                    \
    __syncthreads();                                      \
  } while (0)

#if __has_builtin(__builtin_amdgcn_exp2f)
#define EXP2F(x) __builtin_amdgcn_exp2f(x)
#else
#define EXP2F(x) exp2f(x)
#endif

static __device__ __forceinline__ unsigned short f2bf(float f) {
  unsigned int u = __float_as_uint(f);
  u += 0x7fffu + ((u >> 16) & 1u);          // RNE
  return (unsigned short)(u >> 16);
}

static __device__ __forceinline__ unsigned cvtpk(float lo, float hi) {
  unsigned r;
  asm("v_cvt_pk_bf16_f32 %0, %1, %2" : "=v"(r) : "v"(lo), "v"(hi));
  return r;
}

// ---------------------------------------------------------------------------
// 1) prep (fused): blocks [0,2048): x,y -> XY bf16, z -> Z bf16;
//    blocks [2048,3072): 4x weight f32 -> bf16 transpose (256 blocks each).
// ---------------------------------------------------------------------------
__global__ __launch_bounds__(256) void prep(const float* __restrict__ x,
                                            const float* __restrict__ y,
                                            const float* __restrict__ z,
                                            const float* __restrict__ Wq,
                                            const float* __restrict__ Wk,
                                            const float* __restrict__ Wv,
                                            const float* __restrict__ Wo,
                                            unsigned short* __restrict__ XY,
                                            unsigned short* __restrict__ Z,
                                            unsigned short* __restrict__ WqT,
                                            unsigned short* __restrict__ WkT,
                                            unsigned short* __restrict__ WvT,
                                            unsigned short* __restrict__ WoT) {
  __shared__ __align__(16) unsigned short LT[64 * 72];
  const int bid = blockIdx.x, t = threadIdx.x;

  if (bid < 2048) {
    const int NX = (8192 * 512) / 4;
    const int NZ = (8192 * 1024) / 4;
    const int total = 2 * NX + NZ;
    for (int idx = bid * 256 + t; idx < total; idx += 2048 * 256) {
      const float* src;
      unsigned short* dst;
      if (idx < NX) {
        int p = idx * 4; int row = p >> 9, c = p & 511;
        src = x + p; dst = XY + (size_t)row * 1024 + c;
      } else if (idx < 2 * NX) {
        int p = (idx - NX) * 4; int row = p >> 9, c = p & 511;
        src = y + p; dst = XY + (size_t)row * 1024 + 512 + c;
      } else {
        int p = (idx - 2 * NX) * 4;
        src = z + p; dst = Z + p;
      }
      float4 v = *(const float4*)src;
      us4 o; o[0] = f2bf(v.x); o[1] = f2bf(v.y); o[2] = f2bf(v.z); o[3] = f2bf(v.w);
      *(us4*)dst = o;
    }
    return;
  }

  const int seg = (bid - 2048) >> 8;          // 0..3
  const int local = (bid - 2048) & 255;
  const float* W = (seg == 0) ? Wq : (seg == 1) ? Wk : (seg == 2) ? Wv : Wo;
  unsigned short* WT = (seg == 0) ? WqT : (seg == 1) ? WkT : (seg == 2) ? WvT : WoT;
  const int k0 = (local >> 4) * 64, n0 = (local & 15) * 64;
#pragma unroll
  for (int j = 0; j < 4; ++j) {
    int r = j * 16 + (t >> 4);
    int c = (t & 15) * 4;
    float4 w = *(const float4*)(W + (size_t)(k0 + r) * 1024 + n0 + c);
    LT[(c + 0) * 72 + r] = f2bf(w.x);
    LT[(c + 1) * 72 + r] = f2bf(w.y);
    LT[(c + 2) * 72 + r] = f2bf(w.z);
    LT[(c + 3) * 72 + r] = f2bf(w.w);
  }
  __syncthreads();
#pragma unroll
  for (int j = 0; j < 2; ++j) {
    int n = j * 32 + (t >> 3), ch = t & 7;
    *(short8*)(WT + (size_t)(n0 + n) * 1024 + k0 + ch * 8) =
        *(const short8*)(LT + n * 72 + ch * 8);
  }
}

// ---------------------------------------------------------------------------
// 2a) fused QKV projection, BK=64 (r13/r14-proven, ~62us). V segment stores
//     directly into Vt[bh][d][s] (vtrans eliminated).
// ---------------------------------------------------------------------------
__global__ __launch_bounds__(256) void qkv_gemm(const unsigned short* __restrict__ XY,
                                                const unsigned short* __restrict__ Zb,
                                                const unsigned short* __restrict__ WqT,
                                                const unsigned short* __restrict__ WkT,
                                                const unsigned short* __restrict__ WvT,
                                                unsigned short* __restrict__ Qb,
                                                unsigned short* __restrict__ Kb,
                                                unsigned short* __restrict__ Vtg) {
  __shared__ __align__(16) unsigned short As[128 * 64];
  __shared__ __align__(16) unsigned short Bs[128 * 64];
  const int tid = threadIdx.x;
  const int lane = tid & 63, wid = tid >> 6;
  const int lq = lane & 15, lg = lane >> 4;
  const int wr = wid >> 1, wc = wid & 1;
  const int seg = blockIdx.x >> 3;
  const int m0 = blockIdx.y * 128, n0 = (blockIdx.x & 7) * 128;

  const unsigned short* A;
  const unsigned short* Bt;
  float scale;
  if (seg == 0)      { A = XY; Bt = WqT; scale = 0.18033688011112042f; }
  else if (seg == 1) { A = Zb; Bt = WkT; scale = 1.0f; }
  else               { A = Zb; Bt = WvT; scale = 1.0f; }

  const int srr = tid >> 3;                 // 0..31
  const int gg = (tid & 7) ^ (srr & 7);     // source chunk (pre-swizzled)

  f32x4 acc[4][4] = {};

  for (int k0 = 0; k0 < 1024; k0 += 64) {
    __syncthreads();
#pragma unroll
    for (int i = 0; i < 4; ++i) {
      int r = i * 32 + srr;
      GLOAD16(A + (size_t)(m0 + r) * 1024 + k0 + gg * 8,
              (char*)As + i * 4096 + wid * 1024);
      GLOAD16(Bt + (size_t)(n0 + r) * 1024 + k0 + gg * 8,
              (char*)Bs + i * 4096 + wid * 1024);
    }
    VMEM_DRAIN_BARRIER();
#pragma unroll
    for (int kk = 0; kk < 2; ++kk) {
      short8 af[4], bfr[4];
#pragma unroll
      for (int mf = 0; mf < 4; ++mf) {
        int r = wr * 64 + mf * 16 + lq;
        int c = (kk * 4 + lg) ^ (r & 7);
        af[mf] = *(const short8*)(As + r * 64 + c * 8);
      }
#pragma unroll
      for (int nf = 0; nf < 4; ++nf) {
        int r = wc * 64 + nf * 16 + lq;
        int c = (kk * 4 + lg) ^ (r & 7);
        bfr[nf] = *(const short8*)(Bs + r * 64 + c * 8);
      }
#pragma unroll
      for (int mf = 0; mf < 4; ++mf)
#pragma unroll
        for (int nf = 0; nf < 4; ++nf)
          acc[mf][nf] = __builtin_amdgcn_mfma_f32_16x16x32_bf16(af[mf], bfr[nf],
                                                                acc[mf][nf], 0, 0, 0);
    }
  }

  if (seg == 2) {
    // direct transposed store: Vt[(b*16+h)*64 + d][s], 8B per (mf,nf)
    const int bq = m0 >> 11;                  // batch (tile never crosses b)
    const int sbase = (m0 & 2047) + wr * 64;
#pragma unroll
    for (int mf = 0; mf < 4; ++mf)
#pragma unroll
      for (int nf = 0; nf < 4; ++nf) {
        int col = n0 + wc * 64 + nf * 16 + lq;
        int hh = col >> 6, dd = col & 63;
        int s = sbase + mf * 16 + lg * 4;
        us4 o4;
#pragma unroll
        for (int j = 0; j < 4; ++j) o4[j] = f2bf(acc[mf][nf][j]);
        *(us4*)(Vtg + ((size_t)(bq * 16 + hh) * 64 + dd) * 2048 + s) = o4;
      }
  } else {
    unsigned short* C = (seg == 0) ? Qb : Kb;
#pragma unroll
    for (int mf = 0; mf < 4; ++mf)
#pragma unroll
      for (int nf = 0; nf < 4; ++nf)
#pragma unroll
        for (int j = 0; j < 4; ++j) {
          int row = m0 + wr * 64 + mf * 16 + lg * 4 + j;
          int col = n0 + wc * 64 + nf * 16 + lq;
          C[(size_t)row * 1024 + col] = f2bf(acc[mf][nf][j] * scale);
        }
  }
}

// ---------------------------------------------------------------------------
// 2b) NT GEMM (Wo): C[8192][1024] = A @ Bt^T, f32 out; BK=64 (r13-proven)
// ---------------------------------------------------------------------------
__global__ __launch_bounds__(256) void gemm_nt(const unsigned short* __restrict__ A,
                                               const unsigned short* __restrict__ Bt,
                                               float* __restrict__ Cout) {
  __shared__ __align__(16) unsigned short As[128 * 64];
  __shared__ __align__(16) unsigned short Bs[128 * 64];
  const int tid = threadIdx.x;
  const int lane = tid & 63, wid = tid >> 6;
  const int lq = lane & 15, lg = lane >> 4;
  const int wr = wid >> 1, wc = wid & 1;
  const int m0 = blockIdx.y * 128, n0 = blockIdx.x * 128;

  const int srr = tid >> 3;
  const int gg = (tid & 7) ^ (srr & 7);

  f32x4 acc[4][4] = {};

  for (int k0 = 0; k0 < 1024; k0 += 64) {
    __syncthreads();
#pragma unroll
    for (int i = 0; i < 4; ++i) {
      int r = i * 32 + srr;
      GLOAD16(A + (size_t)(m0 + r) * 1024 + k0 + gg * 8,
              (char*)As + i * 4096 + wid * 1024);
      GLOAD16(Bt + (size_t)(n0 + r) * 1024 + k0 + gg * 8,
              (char*)Bs + i * 4096 + wid * 1024);
    }
    VMEM_DRAIN_BARRIER();
#pragma unroll
    for (int kk = 0; kk < 2; ++kk) {
      short8 af[4], bfr[4];
#pragma unroll
      for (int mf = 0; mf < 4; ++mf) {
        int r = wr * 64 + mf * 16 + lq;
        int c = (kk * 4 + lg) ^ (r & 7);
        af[mf] = *(const short8*)(As + r * 64 + c * 8);
      }
#pragma unroll
      for (int nf = 0; nf < 4; ++nf) {
        int r = wc * 64 + nf * 16 + lq;
        int c = (kk * 4 + lg) ^ (r & 7);
        bfr[nf] = *(const short8*)(Bs + r * 64 + c * 8);
      }
#pragma unroll
      for (int mf = 0; mf < 4; ++mf)
#pragma unroll
        for (int nf = 0; nf < 4; ++nf)
          acc[mf][nf] = __builtin_amdgcn_mfma_f32_16x16x32_bf16(af[mf], bfr[nf],
                                                                acc[mf][nf], 0, 0, 0);
    }
  }

#pragma unroll
  for (int mf = 0; mf < 4; ++mf)
#pragma unroll
    for (int nf = 0; nf < 4; ++nf)
#pragma unroll
      for (int j = 0; j < 4; ++j) {
        int row = m0 + wr * 64 + mf * 16 + lg * 4 + j;
        int col = n0 + wc * 64 + nf * 16 + lq;
        Cout[(size_t)row * 1024 + col] = acc[mf][nf][j];
      }
}

// ---------------------------------------------------------------------------
// 3) flash attention v8 (r10-proven): 8 waves x 32 q = 256 q/block;
//    KVBLK=64 double-buffered; XCD remap; ones-MFMA row-sum; permlane pack.
// ---------------------------------------------------------------------------
__global__ __launch_bounds__(512, 4) void attn8(const unsigned short* __restrict__ Q,
                                                const unsigned short* __restrict__ K,
                                                const unsigned short* __restrict__ Vt,
                                                unsigned short* __restrict__ AO) {
  __shared__ __align__(16) unsigned short Ks[2][64 * 64];  // [kv][d]
  __shared__ __align__(16) unsigned short Vs[2][64 * 64];  // [d][kv]

  const int lin = blockIdx.x + (blockIdx.y << 3);  // 0..511
  const int xcd = lin & 7, rest = lin >> 3;
  const int bh = xcd * 8 + (rest >> 3);
  const int q0 = (rest & 7) * 256;
  const int b = bh >> 4, h = bh & 15;

  const int tid = threadIdx.x, lane = tid & 63, w = tid >> 6;
  const int l31 = lane & 31, hi = lane >> 5;
  const int swz = l31 & 7;

  short8 qf[4];
#pragma unroll
  for (int dblk = 0; dblk < 4; ++dblk)
    qf[dblk] = *(const short8*)(Q + (size_t)(b * 2048 + q0 + w * 32 + l31) * 1024 +
                                h * 64 + dblk * 16 + hi * 8);

  short8 ones;
#pragma unroll
  for (int e = 0; e < 8; ++e) ones[e] = (short)0x3F80;

#define STAGE(bf, t)                                                               \
  do {                                                                             \
    {                                                                              \
      int r = tid >> 3, c = tid & 7, g = c ^ (r & 7);                              \
      GLOAD16(K + (size_t)(b * 2048 + (t) * 64 + r) * 1024 + h * 64 + g * 8,       \
              (char*)Ks[bf] + w * 1024);                                           \
      GLOAD16(Vt + ((size_t)bh * 64 + r) * 2048 + (t) * 64 + g * 8,                \
              (char*)Vs[bf] + w * 1024);                                           \
    }                                                                              \
  } while (0)

  STAGE(0, 0);
  VMEM_DRAIN_BARRIER();

  f32x16 od[2] = {};
  f32x16 sums = {};
  int buf = 0;

  for (int t = 0; t < 32; ++t) {
    if (t < 31) STAGE(buf ^ 1, t + 1);

    f32x16 st[2];
    __builtin_amdgcn_s_setprio(1);
#pragma unroll
    for (int kh = 0; kh < 2; ++kh) {
      f32x16 a = {};
#pragma unroll
      for (int dblk = 0; dblk < 4; ++dblk) {
        short8 kf = *(const short8*)(Ks[buf] + (kh * 32 + l31) * 64 +
                                     (((dblk * 2 + hi) ^ swz) * 8));
        a = __builtin_amdgcn_mfma_f32_32x32x16_bf16(kf, qf[dblk], a, 0, 0, 0);
      }
      st[kh] = a;
    }
    __builtin_amdgcn_s_setprio(0);

#pragma unroll
    for (int kh = 0; kh < 2; ++kh)
#pragma unroll
      for (int r = 0; r < 16; ++r) st[kh][r] = EXP2F(st[kh][r]);

    __builtin_amdgcn_s_setprio(1);
#pragma unroll
    for (int ks = 0; ks < 4; ++ks) {
      const int tt = ks >> 1, cm = (ks & 1) * 2;
      unsigned a_lo = cvtpk(st[tt][cm * 4 + 0], st[tt][cm * 4 + 1]);
      unsigned a_hi = cvtpk(st[tt][cm * 4 + 2], st[tt][cm * 4 + 3]);
      unsigned b_lo = cvtpk(st[tt][cm * 4 + 4], st[tt][cm * 4 + 5]);
      unsigned b_hi = cvtpk(st[tt][cm * 4 + 6], st[tt][cm * 4 + 7]);
      auto Xlo = __builtin_amdgcn_permlane32_swap(a_lo, b_lo, false, false);
      auto Xhi = __builtin_amdgcn_permlane32_swap(a_hi, b_hi, false, false);
      u32x4 up;
      up[0] = Xlo[0];
      up[1] = Xhi[0];
      up[2] = Xlo[1];
      up[3] = Xhi[1];
      short8 pa = __builtin_bit_cast(short8, up);
      sums = __builtin_amdgcn_mfma_f32_32x32x16_bf16(ones, pa, sums, 0, 0, 0);
#pragma unroll
      for (int td = 0; td < 2; ++td) {
        short8 vf = *(const short8*)(Vs[buf] + (td * 32 + l31) * 64 +
                                     (((ks * 2 + hi) ^ swz) * 8));
        od[td] = __builtin_amdgcn_mfma_f32_32x32x16_bf16(vf, pa, od[td], 0, 0, 0);
      }
    }
    __builtin_amdgcn_s_setprio(0);

    VMEM_DRAIN_BARRIER();
    buf ^= 1;
  }

  float inv = 1.0f / sums[0];
  const size_t orow = (size_t)(b * 2048 + q0 + w * 32 + l31);
#pragma unroll
  for (int td = 0; td < 2; ++td)
#pragma unroll
    for (int rh = 0; rh < 4; ++rh) {
      us4 o4;
#pragma unroll
      for (int rl = 0; rl < 4; ++rl) o4[rl] = f2bf(od[td][rh * 4 + rl] * inv);
      *(us4*)(AO + orow * 1024 + h * 64 + td * 32 + rh * 8 + hi * 4) = o4;
    }
#undef STAGE
}

// ---------------------------------------------------------------------------
extern "C" void kernel_launch(void* const* d_in, const int* in_sizes, int n_in,
                              void* d_out, int out_size, void* d_ws, size_t ws_size,
                              hipStream_t stream) {
  const float* x = (const float*)d_in[0];
  const float* y = (const float*)d_in[1];
  const float* z = (const float*)d_in[2];
  const float* Wq = (const float*)d_in[3];
  const float* Wk = (const float*)d_in[4];
  const float* Wv = (const float*)d_in[5];
  const float* Wo = (const float*)d_in[6];

  char* ws = (char*)d_ws;
  unsigned short* XY  = (unsigned short*)(ws + 0);
  unsigned short* Zb  = (unsigned short*)(ws + 16777216);
  unsigned short* WqT = (unsigned short*)(ws + 33554432);
  unsigned short* WkT = (unsigned short*)(ws + 35651584);
  unsigned short* WvT = (unsigned short*)(ws + 37748736);
  unsigned short* WoT = (unsigned short*)(ws + 39845888);
  unsigned short* Qb  = (unsigned short*)(ws + 41943040);
  unsigned short* Kb  = (unsigned short*)(ws + 58720256);
  unsigned short* Vtg = (unsigned short*)(ws + 92274688);
  unsigned short* AO  = (unsigned short*)(ws + 109051904);

  prep<<<3072, 256, 0, stream>>>(x, y, z, Wq, Wk, Wv, Wo,
                                 XY, Zb, WqT, WkT, WvT, WoT);

  // fused QKV projection; V direct to Vt[bh][d][s]
  qkv_gemm<<<dim3(24, 64), 256, 0, stream>>>(XY, Zb, WqT, WkT, WvT, Qb, Kb, Vtg);

  attn8<<<dim3(8, 64), 512, 0, stream>>>(Qb, Kb, Vtg, AO);

  gemm_nt<<<dim3(8, 64), 256, 0, stream>>>(AO, WoT, (float*)d_out);
}